// Round 13
// baseline (46.521 us; speedup 1.0000x reference)
//
#include <hip/hip_runtime.h>
#include <stdint.h>

// Problem constants (from setup_inputs in the reference)
#define BB    4
#define NCAM  6
#define HF    64
#define WF    176
#define IMGPIX (HF * WF)               // 11264
#define NIMG  (BB * NCAM)              // 24
#define NPIX  (NIMG * IMGPIX)          // 270336
#define NEDGE 49
#define SENTINEL 0x7F7F7F7F            // fallback path: memset-able, > any label

// ---- f32-semantics toggles (validated: absmax 0 in rounds 4-12) ----
#define GER_FMA     1
#define TRSM_RECIP  1
#define TRSM_FMA    1

// ---------------------------------------------------------------------------
// np.linalg.inv(float32) emulation = LAPACK sgesv(A, I). Validated bit-exact
// (absmax 0, R4-R12). fp contract(off) INSIDE the function (lexically scoped;
// R7 lesson). Runs only in the tiny 24-thread prep kernel — its
// runtime-indexed arrays (scratch) must stay OUT of the hot kernel (R9 lesson).
// ---------------------------------------------------------------------------
__device__ void inv4_sgesv(const float* __restrict__ m,   // 4x4 cam2ego
                           const float* __restrict__ K,   // 3x3 intrinsics
                           float* __restrict__ out) {     // 16 floats
#pragma clang fp contract(off)
    float a[4][4];
    for (int i = 0; i < 4; ++i)
        for (int j = 0; j < 4; ++j)
            a[i][j] = m[i * 4 + j];

    // ---- sgetf2: right-looking LU with partial pivoting ----
    int ipiv[4];
    for (int j = 0; j < 4; ++j) {
        int p = j;
        float best = fabsf(a[j][j]);
        for (int i = j + 1; i < 4; ++i) {
            float v = fabsf(a[i][j]);
            if (v > best) { best = v; p = i; }
        }
        ipiv[j] = p;
        if (p != j) {
            for (int k = 0; k < 4; ++k) {
                float t = a[j][k]; a[j][k] = a[p][k]; a[p][k] = t;
            }
        }
        float r = 1.0f / a[j][j];
        for (int i = j + 1; i < 4; ++i) a[i][j] = a[i][j] * r;
        for (int k = j + 1; k < 4; ++k) {
            float temp = -a[j][k];
            for (int i = j + 1; i < 4; ++i) {
#if GER_FMA
                a[i][k] = __builtin_fmaf(a[i][j], temp, a[i][k]);
#else
                a[i][k] = a[i][k] + a[i][j] * temp;
#endif
            }
        }
    }

    // ---- sgetrs on B = I ----
    float bmat[4][4];
    for (int i = 0; i < 4; ++i)
        for (int j = 0; j < 4; ++j)
            bmat[i][j] = (i == j) ? 1.0f : 0.0f;

    for (int k = 0; k < 4; ++k) {
        int p = ipiv[k];
        if (p != k) {
            for (int c = 0; c < 4; ++c) {
                float t = bmat[k][c]; bmat[k][c] = bmat[p][c]; bmat[p][c] = t;
            }
        }
    }

    // trsm: Left, Lower, NoTrans, Unit
    for (int c = 0; c < 4; ++c) {
        for (int k = 0; k < 4; ++k) {
            float bk = bmat[k][c];
            for (int i = k + 1; i < 4; ++i) {
#if TRSM_FMA
                bmat[i][c] = __builtin_fmaf(a[i][k], -bk, bmat[i][c]);
#else
                bmat[i][c] = bmat[i][c] - a[i][k] * bk;
#endif
            }
        }
    }

    // trsm: Left, Upper, NoTrans, NonUnit (reciprocal diagonal)
#if TRSM_RECIP
    float rdiag[4];
    for (int k = 0; k < 4; ++k) rdiag[k] = 1.0f / a[k][k];
#endif
    for (int c = 0; c < 4; ++c) {
        for (int k = 3; k >= 0; --k) {
#if TRSM_RECIP
            bmat[k][c] = bmat[k][c] * rdiag[k];
#else
            bmat[k][c] = bmat[k][c] / a[k][k];
#endif
            float bk = bmat[k][c];
            for (int i = 0; i < k; ++i) {
#if TRSM_FMA
                bmat[i][c] = __builtin_fmaf(a[i][k], -bk, bmat[i][c]);
#else
                bmat[i][c] = bmat[i][c] - a[i][k] * bk;
#endif
            }
        }
    }

    for (int i = 0; i < 3; ++i)
        for (int j = 0; j < 4; ++j)
            out[i * 4 + j] = bmat[i][j];

    out[12] = K[0];  // fx
    out[13] = K[4];  // fy
    out[14] = K[2];  // cx
    out[15] = K[5];  // cy
}

__global__ void prep_cams_f32(const float* __restrict__ intr,
                              const float* __restrict__ c2e,
                              float* __restrict__ cams) {
    int idx = blockIdx.x * blockDim.x + threadIdx.x;
    if (idx >= NIMG) return;
    inv4_sgesv(c2e + idx * 16, intr + idx * 9, cams + idx * 16);
}

// ---------------------------------------------------------------------------
// Projection + closed-form binning. fp contract(off) INSIDE (R7 lesson).
// Bit-exact vs numpy f32 pipeline (validated absmax 0, R4-R12).
// uf/vf use trunc (cvt_i32): == floor on the ok-guarded range (exact *0.25f
// pow2 scale); when !ok, pix is never used (validated R12).
// ---------------------------------------------------------------------------
__device__ __forceinline__ bool project_pair(const float* M, float px, float py,
                                             float pz, float lo, float hi,
                                             int& pix, int& label) {
#pragma clang fp contract(off)
    // numpy einsum tail: accum=0; j=3,2,1,0; separate mul/add (no FMA)
    float x = M[3];  x = x + M[2]  * pz;  x = x + M[1] * py;  x = x + M[0] * px;
    float y = M[7];  y = y + M[6]  * pz;  y = y + M[5] * py;  y = y + M[4] * px;
    float z = M[11]; z = z + M[10] * pz;  z = z + M[9] * py;  z = z + M[8] * px;

    float zc = fmaxf(z, 1e-6f);
    float u = M[12] * (x / zc) + M[14];   // IEEE div, then mul, then add
    float v = M[13] * (y / zc) + M[15];

    bool ok = (z > 0.1f) && (u >= 0.0f) && (u <= 703.0f) &&
              (v >= 0.0f) && (v <= 255.0f);

    int uf = (int)(u * 0.25f);            // trunc == floor on guarded range
    int vf = (int)(v * 0.25f);
    pix = vf * WF + uf;

    // closed-form searchsorted: d-0.5f exact for d in [0.501,48.499]
    float d = fminf(fmaxf(z, lo), hi);
    label = (int)ceilf(d - 0.5f) - 1;     // in [0,47]
    return ok;
}

// ---------------------------------------------------------------------------
// Kernel: 3-images-per-block LDS z-buffer. Block (g, grp) holds cams
// {3*grp, 3*grp+1, 3*grp+2} of batch grp/2 in LDS (3 x 45 KB = 135 KB,
// 1 block/CU — the R9/R11-validated residency optimum) and reads its point
// chunk ONCE for all 3 cams: point-load traffic drops 6x -> 2x per point
// (192 MB -> 64 MB), attacking the feed bound identified in R12.
// 2-point x 3-cam unroll = 6 independent projection pipelines (validated
// ILP sweet spot). Projection semantics byte-identical to R10/R12.
// ---------------------------------------------------------------------------
__global__ __launch_bounds__(1024)
void scatter_lds3(const float4* __restrict__ pts,
                  const float* __restrict__ cams,
                  const float* __restrict__ edges_f,
                  uint8_t* __restrict__ reps,
                  int npts, int csz) {
    __shared__ unsigned sbuf[3 * IMGPIX];      // 135168 B

    int g    = blockIdx.x;
    int grp  = blockIdx.y;                     // 8 groups = 24 images / 3
    int img0 = grp * 3;
    int b    = grp >> 1;                       // img0/6

    // vectorized init: 3*IMGPIX/4 = 8448 uint4 stores
    uint4* s4 = (uint4*)sbuf;
    for (int i = threadIdx.x; i < 3 * IMGPIX / 4; i += 1024)
        s4[i] = make_uint4(0xFFFFFFFFu, 0xFFFFFFFFu, 0xFFFFFFFFu, 0xFFFFFFFFu);
    __syncthreads();

    const float* M0 = cams + (img0 + 0) * 16;  // wave-uniform -> s_load
    const float* M1 = cams + (img0 + 1) * 16;
    const float* M2 = cams + (img0 + 2) * 16;
    float lo = edges_f[0]         + 0.001f;
    float hi = edges_f[NEDGE - 1] - 0.001f;

    int start = g * csz;
    int end   = start + csz; if (end > npts) end = npts;
    const float4* bp = pts + (size_t)b * npts;

    int p = start + (int)threadIdx.x;

    // main: 2 points x 3 cams = 6 independent projection pipelines
    for (; p + 1024 < end; p += 2 * 1024) {
        float4 a0 = bp[p];
        float4 a1 = bp[p + 1024];

        int x00, l00, x01, l01, x10, l10, x11, l11, x20, l20, x21, l21;
        bool k00 = project_pair(M0, a0.x, a0.y, a0.z, lo, hi, x00, l00);
        bool k01 = project_pair(M0, a1.x, a1.y, a1.z, lo, hi, x01, l01);
        bool k10 = project_pair(M1, a0.x, a0.y, a0.z, lo, hi, x10, l10);
        bool k11 = project_pair(M1, a1.x, a1.y, a1.z, lo, hi, x11, l11);
        bool k20 = project_pair(M2, a0.x, a0.y, a0.z, lo, hi, x20, l20);
        bool k21 = project_pair(M2, a1.x, a1.y, a1.z, lo, hi, x21, l21);

        if (k00) atomicMin(&sbuf[x00],              (unsigned)l00);
        if (k01) atomicMin(&sbuf[x01],              (unsigned)l01);
        if (k10) atomicMin(&sbuf[IMGPIX + x10],     (unsigned)l10);
        if (k11) atomicMin(&sbuf[IMGPIX + x11],     (unsigned)l11);
        if (k20) atomicMin(&sbuf[2 * IMGPIX + x20], (unsigned)l20);
        if (k21) atomicMin(&sbuf[2 * IMGPIX + x21], (unsigned)l21);
    }
    // remainder: single point x 3 cams
    for (; p < end; p += 1024) {
        float4 a0 = bp[p];
        int x0, l0, x1, l1, x2, l2;
        if (project_pair(M0, a0.x, a0.y, a0.z, lo, hi, x0, l0))
            atomicMin(&sbuf[x0], (unsigned)l0);
        if (project_pair(M1, a0.x, a0.y, a0.z, lo, hi, x1, l1))
            atomicMin(&sbuf[IMGPIX + x1], (unsigned)l1);
        if (project_pair(M2, a0.x, a0.y, a0.z, lo, hi, x2, l2))
            atomicMin(&sbuf[2 * IMGPIX + x2], (unsigned)l2);
    }
    __syncthreads();

    // writeback: pack 4 labels -> u32; 3 x 2816 coalesced dword stores
    for (int c = 0; c < 3; ++c) {
        unsigned* r32 = (unsigned*)(reps + (size_t)g * NPIX +
                                    (size_t)(img0 + c) * IMGPIX);
        const unsigned* s = &sbuf[c * IMGPIX];
        for (int i = threadIdx.x; i < IMGPIX / 4; i += 1024) {
            unsigned w = (s[4 * i] & 0xFFu)
                       | ((s[4 * i + 1] & 0xFFu) << 8)
                       | ((s[4 * i + 2] & 0xFFu) << 16)
                       | ((s[4 * i + 3] & 0xFFu) << 24);
            r32[i] = w;                        // 255 = empty, else label
        }
    }
}

// ---------------------------------------------------------------------------
// Kernel: merge G replicas, 4 pixels/thread via uint loads (NPIX % 4 == 0).
// Validated absmax 0 in R11/R12.
// ---------------------------------------------------------------------------
__global__ void merge_reps(const uint8_t* __restrict__ reps, int G,
                           int* __restrict__ out) {
    int q = blockIdx.x * blockDim.x + threadIdx.x;   // quad index
    if (q >= NPIX / 4) return;

    unsigned m = 0xFFFFFFFFu;                        // per-byte min, start 255
    for (int g = 0; g < G; ++g) {
        unsigned v = *(const unsigned*)(reps + (size_t)g * NPIX + q * 4);
        unsigned lo0 = (m & 0xFFu),        v0 = (v & 0xFFu);
        unsigned lo1 = (m >> 8) & 0xFFu,   v1 = (v >> 8) & 0xFFu;
        unsigned lo2 = (m >> 16) & 0xFFu,  v2 = (v >> 16) & 0xFFu;
        unsigned lo3 = (m >> 24),          v3 = (v >> 24);
        lo0 = v0 < lo0 ? v0 : lo0;
        lo1 = v1 < lo1 ? v1 : lo1;
        lo2 = v2 < lo2 ? v2 : lo2;
        lo3 = v3 < lo3 ? v3 : lo3;
        m = lo0 | (lo1 << 8) | (lo2 << 16) | (lo3 << 24);
    }
    int4 r;
    unsigned b0 = m & 0xFFu, b1 = (m >> 8) & 0xFFu,
             b2 = (m >> 16) & 0xFFu, b3 = m >> 24;
    r.x = (b0 == 255u) ? -1 : (int)b0;
    r.y = (b1 == 255u) ? -1 : (int)b1;
    r.z = (b2 == 255u) ? -1 : (int)b2;
    r.w = (b3 == 255u) ? -1 : (int)b3;
    ((int4*)out)[q] = r;
}

// ---------------------------------------------------------------------------
// Fallback path (validated R5 semantics) for tiny workspaces.
// ---------------------------------------------------------------------------
__global__ __launch_bounds__(256)
void scatter_minbin(const float4* __restrict__ pts,
                    const float* __restrict__ cams,
                    const float* __restrict__ edges_f,
                    int* __restrict__ out,
                    int npts) {
    int p = blockIdx.x * blockDim.x + threadIdx.x;
    int b = blockIdx.y;
    if (p >= npts) return;

    float4 pt = pts[(size_t)b * npts + p];
    float lo = edges_f[0]         + 0.001f;
    float hi = edges_f[NEDGE - 1] - 0.001f;

#pragma unroll
    for (int n = 0; n < NCAM; ++n) {
        const float* M = cams + (b * NCAM + n) * 16;
        int pix, label;
        if (project_pair(M, pt.x, pt.y, pt.z, lo, hi, pix, label)) {
            atomicMin(&out[(b * NCAM + n) * IMGPIX + pix], label);
        }
    }
}

__global__ void finalize(int* out) {
    int i = blockIdx.x * blockDim.x + threadIdx.x;
    if (i < NPIX && out[i] == SENTINEL) out[i] = -1;
}

// ---------------------------------------------------------------------------
extern "C" void kernel_launch(void* const* d_in, const int* in_sizes, int n_in,
                              void* d_out, int out_size, void* d_ws, size_t ws_size,
                              hipStream_t stream) {
    const float* points    = (const float*)d_in[0];  // (B, Npts, 4) f32
    const float* intrinsic = (const float*)d_in[1];  // (B, Ncam, 3, 3) f32
    const float* cam2ego   = (const float*)d_in[2];  // (B, Ncam, 4, 4) f32
    const float* edges     = (const float*)d_in[3];  // (49,) f32

    int npts = in_sizes[0] / (BB * 4);               // 500000
    int* out = (int*)d_out;

    float*   cams = (float*)d_ws;                    // 1.5 KB at offset 0
    uint8_t* reps = (uint8_t*)d_ws + 2048;           // G replica sets of NPIX u8

    // G = 30 -> 30 x 8 = 240 blocks -> 1 block/CU (validated residency optimum)
    int G = 0;
    if (ws_size > 2048 + (size_t)NPIX)
        G = (int)((ws_size - 2048) / (size_t)NPIX);
    if (G > 30) G = 30;

    prep_cams_f32<<<1, 64, 0, stream>>>(intrinsic, cam2ego, cams);

    if (G >= 1) {
        int csz = (npts + G - 1) / G;
        dim3 grid(G, NIMG / 3);                      // (30, 8)
        scatter_lds3<<<grid, 1024, 0, stream>>>((const float4*)points, cams,
                                                edges, reps, npts, csz);
        merge_reps<<<(NPIX / 4 + 255) / 256, 256, 0, stream>>>(reps, G, out);
    } else {
        // tiny-workspace fallback: validated R5 path
        hipMemsetAsync(out, 0x7F, (size_t)NPIX * sizeof(int), stream);
        dim3 grid((npts + 255) / 256, BB);
        scatter_minbin<<<grid, 256, 0, stream>>>((const float4*)points, cams,
                                                 edges, out, npts);
        finalize<<<(NPIX + 255) / 256, 256, 0, stream>>>(out);
    }
}

// Round 14
// 40.321 us; speedup vs baseline: 1.1538x; 1.1538x over previous
//
#include <hip/hip_runtime.h>
#include <stdint.h>

// Problem constants (from setup_inputs in the reference)
#define BB    4
#define NCAM  6
#define HF    64
#define WF    176
#define IMGPIX (HF * WF)               // 11264
#define NIMG  (BB * NCAM)              // 24
#define NPIX  (NIMG * IMGPIX)          // 270336
#define NEDGE 49
#define SENTINEL 0x7F7F7F7F            // fallback path: memset-able, > any label

// ---- f32-semantics toggles (validated: absmax 0 in rounds 4-13) ----
#define GER_FMA     1
#define TRSM_RECIP  1
#define TRSM_FMA    1

// ---------------------------------------------------------------------------
// np.linalg.inv(float32) emulation = LAPACK sgesv(A, I). Validated bit-exact
// (absmax 0, R4-R13). fp contract(off) INSIDE the function (lexically scoped;
// R7 lesson). Runs only in the tiny 24-thread prep kernel — its
// runtime-indexed arrays (scratch) must stay OUT of the hot kernel (R9 lesson).
// ---------------------------------------------------------------------------
__device__ void inv4_sgesv(const float* __restrict__ m,   // 4x4 cam2ego
                           const float* __restrict__ K,   // 3x3 intrinsics
                           float* __restrict__ out) {     // 16 floats
#pragma clang fp contract(off)
    float a[4][4];
    for (int i = 0; i < 4; ++i)
        for (int j = 0; j < 4; ++j)
            a[i][j] = m[i * 4 + j];

    // ---- sgetf2: right-looking LU with partial pivoting ----
    int ipiv[4];
    for (int j = 0; j < 4; ++j) {
        int p = j;
        float best = fabsf(a[j][j]);
        for (int i = j + 1; i < 4; ++i) {
            float v = fabsf(a[i][j]);
            if (v > best) { best = v; p = i; }
        }
        ipiv[j] = p;
        if (p != j) {
            for (int k = 0; k < 4; ++k) {
                float t = a[j][k]; a[j][k] = a[p][k]; a[p][k] = t;
            }
        }
        float r = 1.0f / a[j][j];
        for (int i = j + 1; i < 4; ++i) a[i][j] = a[i][j] * r;
        for (int k = j + 1; k < 4; ++k) {
            float temp = -a[j][k];
            for (int i = j + 1; i < 4; ++i) {
#if GER_FMA
                a[i][k] = __builtin_fmaf(a[i][j], temp, a[i][k]);
#else
                a[i][k] = a[i][k] + a[i][j] * temp;
#endif
            }
        }
    }

    // ---- sgetrs on B = I ----
    float bmat[4][4];
    for (int i = 0; i < 4; ++i)
        for (int j = 0; j < 4; ++j)
            bmat[i][j] = (i == j) ? 1.0f : 0.0f;

    for (int k = 0; k < 4; ++k) {
        int p = ipiv[k];
        if (p != k) {
            for (int c = 0; c < 4; ++c) {
                float t = bmat[k][c]; bmat[k][c] = bmat[p][c]; bmat[p][c] = t;
            }
        }
    }

    // trsm: Left, Lower, NoTrans, Unit
    for (int c = 0; c < 4; ++c) {
        for (int k = 0; k < 4; ++k) {
            float bk = bmat[k][c];
            for (int i = k + 1; i < 4; ++i) {
#if TRSM_FMA
                bmat[i][c] = __builtin_fmaf(a[i][k], -bk, bmat[i][c]);
#else
                bmat[i][c] = bmat[i][c] - a[i][k] * bk;
#endif
            }
        }
    }

    // trsm: Left, Upper, NoTrans, NonUnit (reciprocal diagonal)
#if TRSM_RECIP
    float rdiag[4];
    for (int k = 0; k < 4; ++k) rdiag[k] = 1.0f / a[k][k];
#endif
    for (int c = 0; c < 4; ++c) {
        for (int k = 3; k >= 0; --k) {
#if TRSM_RECIP
            bmat[k][c] = bmat[k][c] * rdiag[k];
#else
            bmat[k][c] = bmat[k][c] / a[k][k];
#endif
            float bk = bmat[k][c];
            for (int i = 0; i < k; ++i) {
#if TRSM_FMA
                bmat[i][c] = __builtin_fmaf(a[i][k], -bk, bmat[i][c]);
#else
                bmat[i][c] = bmat[i][c] - a[i][k] * bk;
#endif
            }
        }
    }

    for (int i = 0; i < 3; ++i)
        for (int j = 0; j < 4; ++j)
            out[i * 4 + j] = bmat[i][j];

    out[12] = K[0];  // fx
    out[13] = K[4];  // fy
    out[14] = K[2];  // cx
    out[15] = K[5];  // cy
}

__global__ void prep_cams_f32(const float* __restrict__ intr,
                              const float* __restrict__ c2e,
                              float* __restrict__ cams) {
    int idx = blockIdx.x * blockDim.x + threadIdx.x;
    if (idx >= NIMG) return;
    inv4_sgesv(c2e + idx * 16, intr + idx * 9, cams + idx * 16);
}

// ---------------------------------------------------------------------------
// Projection + closed-form binning. fp contract(off) INSIDE (R7 lesson).
// Bit-exact vs numpy f32 pipeline (validated absmax 0, R4-R13).
// uf/vf use trunc (cvt_i32): == floor on the ok-guarded range (exact *0.25f
// pow2 scale); when !ok, pix is never used (validated R12).
// ---------------------------------------------------------------------------
__device__ __forceinline__ bool project_pair(const float* M, float px, float py,
                                             float pz, float lo, float hi,
                                             int& pix, int& label) {
#pragma clang fp contract(off)
    // numpy einsum tail: accum=0; j=3,2,1,0; separate mul/add (no FMA)
    float x = M[3];  x = x + M[2]  * pz;  x = x + M[1] * py;  x = x + M[0] * px;
    float y = M[7];  y = y + M[6]  * pz;  y = y + M[5] * py;  y = y + M[4] * px;
    float z = M[11]; z = z + M[10] * pz;  z = z + M[9] * py;  z = z + M[8] * px;

    float zc = fmaxf(z, 1e-6f);
    float u = M[12] * (x / zc) + M[14];   // IEEE div, then mul, then add
    float v = M[13] * (y / zc) + M[15];

    bool ok = (z > 0.1f) && (u >= 0.0f) && (u <= 703.0f) &&
              (v >= 0.0f) && (v <= 255.0f);

    int uf = (int)(u * 0.25f);            // trunc == floor on guarded range
    int vf = (int)(v * 0.25f);
    pix = vf * WF + uf;

    // closed-form searchsorted: d-0.5f exact for d in [0.501,48.499]
    float d = fminf(fmaxf(z, lo), hi);
    label = (int)ceilf(d - 0.5f) - 1;     // in [0,47]
    return ok;
}

// ---------------------------------------------------------------------------
// Kernel: image-major LDS z-buffer (R10/R12-validated base: one cam/block,
// G=10, wave-uniform M -> s_load, zero scratch), now with CROSS-ITERATION
// REGISTER PREFETCH: iteration i's 4 point loads are issued during iteration
// i-1's compute (~1000 cy), hiding the ~200-900 cy L2/HBM load latency the
// compiler won't pipeline across the loop-carried boundary (R13 diagnosis:
// VALUBusy 50% == compute/(compute+latency) almost exactly).
// Prefetch addresses clamped to npts-1: always in-bounds; values are
// discarded when the loop exits (remainder loop re-reads directly).
// ---------------------------------------------------------------------------
__global__ __launch_bounds__(1024)
void scatter_lds(const float4* __restrict__ pts,
                 const float* __restrict__ cams,
                 const float* __restrict__ edges_f,
                 uint8_t* __restrict__ reps,
                 int npts, int csz) {
    __shared__ unsigned sbuf[IMGPIX];          // 45056 B

    int g   = blockIdx.x;
    int img = blockIdx.y;                      // b*6 + n
    int b   = img / NCAM;

    uint4* s4 = (uint4*)sbuf;
    for (int i = threadIdx.x; i < IMGPIX / 4; i += 1024)
        s4[i] = make_uint4(0xFFFFFFFFu, 0xFFFFFFFFu, 0xFFFFFFFFu, 0xFFFFFFFFu);
    __syncthreads();

    const float* M = cams + img * 16;          // wave-uniform -> scalar loads
    float lo = edges_f[0]         + 0.001f;
    float hi = edges_f[NEDGE - 1] - 0.001f;

    int start = g * csz;
    int end   = start + csz; if (end > npts) end = npts;
    const float4* bp = pts + (size_t)b * npts;
    int last = npts - 1;

    int p = start + (int)threadIdx.x;

    // prologue: load current group (clamped; only consumed if loop entered)
    int q0 = p              ; if (q0 > last) q0 = last;
    int q1 = p + 1024       ; if (q1 > last) q1 = last;
    int q2 = p + 2048       ; if (q2 > last) q2 = last;
    int q3 = p + 3072       ; if (q3 > last) q3 = last;
    float4 c0 = bp[q0], c1 = bp[q1], c2 = bp[q2], c3 = bp[q3];

    // main: compute current 4 while next 4 loads are in flight
    for (; p + 3 * 1024 < end; p += 4 * 1024) {
        int n0 = p + 4096; if (n0 > last) n0 = last;
        int n1 = p + 5120; if (n1 > last) n1 = last;
        int n2 = p + 6144; if (n2 > last) n2 = last;
        int n3 = p + 7168; if (n3 > last) n3 = last;
        float4 f0 = bp[n0], f1 = bp[n1], f2 = bp[n2], f3 = bp[n3];  // prefetch

        int px0, l0, px1, l1, px2, l2, px3, l3;
        bool k0 = project_pair(M, c0.x, c0.y, c0.z, lo, hi, px0, l0);
        bool k1 = project_pair(M, c1.x, c1.y, c1.z, lo, hi, px1, l1);
        bool k2 = project_pair(M, c2.x, c2.y, c2.z, lo, hi, px2, l2);
        bool k3 = project_pair(M, c3.x, c3.y, c3.z, lo, hi, px3, l3);

        if (k0) atomicMin(&sbuf[px0], (unsigned)l0);
        if (k1) atomicMin(&sbuf[px1], (unsigned)l1);
        if (k2) atomicMin(&sbuf[px2], (unsigned)l2);
        if (k3) atomicMin(&sbuf[px3], (unsigned)l3);

        c0 = f0; c1 = f1; c2 = f2; c3 = f3;
    }
    // remainder: direct reads
    for (; p < end; p += 1024) {
        float4 a0 = bp[p];
        int px0, l0;
        if (project_pair(M, a0.x, a0.y, a0.z, lo, hi, px0, l0))
            atomicMin(&sbuf[px0], (unsigned)l0);
    }
    __syncthreads();

    // writeback: pack 4 labels -> u32, 2816 coalesced dword stores
    unsigned* r32 = (unsigned*)(reps + (size_t)g * NPIX + (size_t)img * IMGPIX);
    for (int i = threadIdx.x; i < IMGPIX / 4; i += 1024) {
        unsigned w = (sbuf[4 * i] & 0xFFu)
                   | ((sbuf[4 * i + 1] & 0xFFu) << 8)
                   | ((sbuf[4 * i + 2] & 0xFFu) << 16)
                   | ((sbuf[4 * i + 3] & 0xFFu) << 24);
        r32[i] = w;                            // 255 = empty, else label
    }
}

// ---------------------------------------------------------------------------
// Kernel: merge G replicas, 4 pixels/thread via uint loads (NPIX % 4 == 0).
// Validated absmax 0 in R11-R13.
// ---------------------------------------------------------------------------
__global__ void merge_reps(const uint8_t* __restrict__ reps, int G,
                           int* __restrict__ out) {
    int q = blockIdx.x * blockDim.x + threadIdx.x;   // quad index
    if (q >= NPIX / 4) return;

    unsigned m = 0xFFFFFFFFu;                        // per-byte min, start 255
    for (int g = 0; g < G; ++g) {
        unsigned v = *(const unsigned*)(reps + (size_t)g * NPIX + q * 4);
        unsigned lo0 = (m & 0xFFu),        v0 = (v & 0xFFu);
        unsigned lo1 = (m >> 8) & 0xFFu,   v1 = (v >> 8) & 0xFFu;
        unsigned lo2 = (m >> 16) & 0xFFu,  v2 = (v >> 16) & 0xFFu;
        unsigned lo3 = (m >> 24),          v3 = (v >> 24);
        lo0 = v0 < lo0 ? v0 : lo0;
        lo1 = v1 < lo1 ? v1 : lo1;
        lo2 = v2 < lo2 ? v2 : lo2;
        lo3 = v3 < lo3 ? v3 : lo3;
        m = lo0 | (lo1 << 8) | (lo2 << 16) | (lo3 << 24);
    }
    int4 r;
    unsigned b0 = m & 0xFFu, b1 = (m >> 8) & 0xFFu,
             b2 = (m >> 16) & 0xFFu, b3 = m >> 24;
    r.x = (b0 == 255u) ? -1 : (int)b0;
    r.y = (b1 == 255u) ? -1 : (int)b1;
    r.z = (b2 == 255u) ? -1 : (int)b2;
    r.w = (b3 == 255u) ? -1 : (int)b3;
    ((int4*)out)[q] = r;
}

// ---------------------------------------------------------------------------
// Fallback path (validated R5 semantics) for tiny workspaces.
// ---------------------------------------------------------------------------
__global__ __launch_bounds__(256)
void scatter_minbin(const float4* __restrict__ pts,
                    const float* __restrict__ cams,
                    const float* __restrict__ edges_f,
                    int* __restrict__ out,
                    int npts) {
    int p = blockIdx.x * blockDim.x + threadIdx.x;
    int b = blockIdx.y;
    if (p >= npts) return;

    float4 pt = pts[(size_t)b * npts + p];
    float lo = edges_f[0]         + 0.001f;
    float hi = edges_f[NEDGE - 1] - 0.001f;

#pragma unroll
    for (int n = 0; n < NCAM; ++n) {
        const float* M = cams + (b * NCAM + n) * 16;
        int pix, label;
        if (project_pair(M, pt.x, pt.y, pt.z, lo, hi, pix, label)) {
            atomicMin(&out[(b * NCAM + n) * IMGPIX + pix], label);
        }
    }
}

__global__ void finalize(int* out) {
    int i = blockIdx.x * blockDim.x + threadIdx.x;
    if (i < NPIX && out[i] == SENTINEL) out[i] = -1;
}

// ---------------------------------------------------------------------------
extern "C" void kernel_launch(void* const* d_in, const int* in_sizes, int n_in,
                              void* d_out, int out_size, void* d_ws, size_t ws_size,
                              hipStream_t stream) {
    const float* points    = (const float*)d_in[0];  // (B, Npts, 4) f32
    const float* intrinsic = (const float*)d_in[1];  // (B, Ncam, 3, 3) f32
    const float* cam2ego   = (const float*)d_in[2];  // (B, Ncam, 4, 4) f32
    const float* edges     = (const float*)d_in[3];  // (49,) f32

    int npts = in_sizes[0] / (BB * 4);               // 500000
    int* out = (int*)d_out;

    float*   cams = (float*)d_ws;                    // 1.5 KB at offset 0
    uint8_t* reps = (uint8_t*)d_ws + 2048;           // G replica sets of NPIX u8

    // G = 10 -> 240 blocks -> 1 block/CU (validated optimum across R8-R13)
    int G = 0;
    if (ws_size > 2048 + (size_t)NPIX)
        G = (int)((ws_size - 2048) / (size_t)NPIX);
    if (G > 10) G = 10;

    prep_cams_f32<<<1, 64, 0, stream>>>(intrinsic, cam2ego, cams);

    if (G >= 1) {
        int csz = (npts + G - 1) / G;
        dim3 grid(G, NIMG);
        scatter_lds<<<grid, 1024, 0, stream>>>((const float4*)points, cams,
                                               edges, reps, npts, csz);
        merge_reps<<<(NPIX / 4 + 255) / 256, 256, 0, stream>>>(reps, G, out);
    } else {
        // tiny-workspace fallback: validated R5 path
        hipMemsetAsync(out, 0x7F, (size_t)NPIX * sizeof(int), stream);
        dim3 grid((npts + 255) / 256, BB);
        scatter_minbin<<<grid, 256, 0, stream>>>((const float4*)points, cams,
                                                 edges, out, npts);
        finalize<<<(NPIX + 255) / 256, 256, 0, stream>>>(out);
    }
}